// Round 7
// baseline (2413.890 us; speedup 1.0000x reference)
//
#include <hip/hip_runtime.h>
#include <math.h>

#define B_    32
#define T_    512
#define WDIM_ 300
#define H_    256
#define G4_   1024            // 4*H
#define M_    (B_ * T_)       // 16384

// persistent-LSTM geometry: team = 8 WGs covering one (dir, batch-pair)
#define NCG   8               // col groups per team (32 d's each)
#define NWG   256             // 2 dirs * 16 batch-pairs * NCG
#define THR   512

// h exchange: plain-float buffer + per-producer flags (both parity-doubled)
// hh   : float [2 par][2 dir][16 bg][512]   (512 = d*2 + row)
// flags: uint  [2 par][2 dir][16 bg][8 cg]
#define HHN   (2 * 2 * 16 * 512)
#define FLN   (2 * 2 * 16 * 8)

// repeat macros -> compile-time-constant indices (SROA-safe register arrays)
#define RPT4(M, b)  M(b) M((b)+1) M((b)+2) M((b)+3)
#define RPT16(M, b) RPT4(M, b) RPT4(M, (b)+4) RPT4(M, (b)+8) RPT4(M, (b)+12)
#define RPT64(M)    RPT16(M, 0) RPT16(M, 16) RPT16(M, 32) RPT16(M, 48)

// fast gate math: v_exp_f32 + v_rcp_f32 (|rel err| ~1e-6; validated R5/R6)
__device__ __forceinline__ float fsigm(float x) {
    return __builtin_amdgcn_rcpf(1.f + __expf(-x));
}
__device__ __forceinline__ float ftanh(float x) {
    const float ax = fabsf(x);
    const float t  = 1.f - 2.f * __builtin_amdgcn_rcpf(__expf(2.f * ax) + 1.f);
    return copysignf(t, x);
}

// ---------------------------------------------------------------------------
// Kernel 1: z = relu(emb[x] @ W_in + b_in)   [16384,300]@[300,256]
// ---------------------------------------------------------------------------
__global__ __launch_bounds__(256)
void k_embed_proj(const float* __restrict__ emb, const float* __restrict__ Win,
                  const float* __restrict__ bin, const int* __restrict__ x,
                  float* __restrict__ z)
{
    __shared__ float Ash[16][132];
    __shared__ float Bsh[16][132];
    __shared__ int   rows[128];

    const int tid = threadIdx.x;
    const int tx = tid & 15, ty = tid >> 4;
    const int rm = blockIdx.y * 128;
    const int cn = blockIdx.x * 128;

    if (tid < 128) rows[tid] = x[rm + tid];
    __syncthreads();

    float acc[8][8];
#pragma unroll
    for (int i = 0; i < 8; ++i)
#pragma unroll
        for (int j = 0; j < 8; ++j) acc[i][j] = 0.f;

    for (int kc = 0; kc < 19; ++kc) {
        const int k0 = kc * 16;
#pragma unroll
        for (int e = 0; e < 8; ++e) {
            const int idx = e * 256 + tid;
            const int r = idx >> 4, kk = idx & 15;
            const int k = k0 + kk;
            const int v = rows[r];
            Ash[kk][r] = (k < WDIM_) ? emb[(size_t)v * WDIM_ + k] : 0.f;
        }
#pragma unroll
        for (int e = 0; e < 8; ++e) {
            const int idx = e * 256 + tid;
            const int kk = idx >> 7, n = idx & 127;
            const int k = k0 + kk;
            Bsh[kk][n] = (k < WDIM_) ? Win[(size_t)k * H_ + cn + n] : 0.f;
        }
        __syncthreads();
#pragma unroll
        for (int kk = 0; kk < 16; ++kk) {
            float a[8], bb[8];
#pragma unroll
            for (int i = 0; i < 8; ++i) a[i] = Ash[kk][ty * 8 + i];
#pragma unroll
            for (int j = 0; j < 8; ++j) bb[j] = Bsh[kk][tx * 8 + j];
#pragma unroll
            for (int i = 0; i < 8; ++i)
#pragma unroll
                for (int j = 0; j < 8; ++j) acc[i][j] += a[i] * bb[j];
        }
        __syncthreads();
    }

#pragma unroll
    for (int i = 0; i < 8; ++i) {
        const int row = rm + ty * 8 + i;
#pragma unroll
        for (int j = 0; j < 8; ++j) {
            const int col = cn + tx * 8 + j;
            z[(size_t)row * H_ + col] = fmaxf(acc[i][j] + bin[col], 0.f);
        }
    }
}

// ---------------------------------------------------------------------------
// Kernel 2: P_d = z @ Wih_d + bl_d  (both directions via blockIdx.z)
// ---------------------------------------------------------------------------
__global__ __launch_bounds__(256)
void k_in_proj(const float* __restrict__ z,
               const float* __restrict__ Wf, const float* __restrict__ blf,
               const float* __restrict__ Wb, const float* __restrict__ blb,
               float* __restrict__ Pf, float* __restrict__ Pb)
{
    const float* W  = blockIdx.z ? Wb  : Wf;
    const float* bl = blockIdx.z ? blb : blf;
    float*       P  = blockIdx.z ? Pb  : Pf;

    __shared__ float Ash[16][132];
    __shared__ float Bsh[16][132];

    const int tid = threadIdx.x;
    const int tx = tid & 15, ty = tid >> 4;
    const int rm = blockIdx.y * 128;
    const int cn = blockIdx.x * 128;

    float acc[8][8];
#pragma unroll
    for (int i = 0; i < 8; ++i)
#pragma unroll
        for (int j = 0; j < 8; ++j) acc[i][j] = 0.f;

    for (int kc = 0; kc < 16; ++kc) {
        const int k0 = kc * 16;
#pragma unroll
        for (int e = 0; e < 8; ++e) {
            const int idx = e * 256 + tid;
            const int r = idx >> 4, kk = idx & 15;
            Ash[kk][r] = z[(size_t)(rm + r) * H_ + k0 + kk];
        }
#pragma unroll
        for (int e = 0; e < 8; ++e) {
            const int idx = e * 256 + tid;
            const int kk = idx >> 7, n = idx & 127;
            Bsh[kk][n] = W[(size_t)(k0 + kk) * G4_ + cn + n];
        }
        __syncthreads();
#pragma unroll
        for (int kk = 0; kk < 16; ++kk) {
            float a[8], bb[8];
#pragma unroll
            for (int i = 0; i < 8; ++i) a[i] = Ash[kk][ty * 8 + i];
#pragma unroll
            for (int j = 0; j < 8; ++j) bb[j] = Bsh[kk][tx * 8 + j];
#pragma unroll
            for (int i = 0; i < 8; ++i)
#pragma unroll
                for (int j = 0; j < 8; ++j) acc[i][j] += a[i] * bb[j];
        }
        __syncthreads();
    }

#pragma unroll
    for (int i = 0; i < 8; ++i) {
        const int row = rm + ty * 8 + i;
#pragma unroll
        for (int j = 0; j < 8; ++j) {
            const int col = cn + tx * 8 + j;
            P[(size_t)row * G4_ + col] = acc[i][j] + bl[col];
        }
    }
}

// ---------------------------------------------------------------------------
// Init: zero h buffers (h=0 initial state) and flags (step counter 0)
// ---------------------------------------------------------------------------
__global__ void k_init(float* __restrict__ hh, unsigned int* __restrict__ flg)
{
    const int i = blockIdx.x * blockDim.x + threadIdx.x;
    if (i < HHN) hh[i] = 0.f;
    if (i < FLN) flg[i] = 0u;
}

// ---------------------------------------------------------------------------
// Kernel 3: persistent bidirectional LSTM recurrence — flag+bulk protocol.
// WG = (dir, batch-pair, colgroup of 32 hiddens). Team = 8 colgroups.
// Publish: gate wave stores h (4B relaxed agent atomics, cache-bypassing) ->
// wave release fence (s_waitcnt vmcnt(0)) -> ONE flag store (=s+1, parity).
// Consume: wave w spins on the single flag of producer cg'=w (one broadcast
// dword load per wave, 8 flags/team vs 512 packets in R4) -> per-thread 4B
// cache-bypass h load -> LDS stage; __syncthreads joins all 8 observations.
// Compute core (reg-resident Whh via RPT, zp k-split reduce) = R4 verbatim.
// Overwrite safety: all h reads happen-before publish via the two barriers,
// and parity slots alternate — identical invariant to R4 (absmax 0.0).
// ---------------------------------------------------------------------------
__global__ __launch_bounds__(THR, 2)
void k_lstm_persist(const float* __restrict__ Pf, const float* __restrict__ Pb,
                    const float* __restrict__ Whf, const float* __restrict__ Whb,
                    const int* __restrict__ lengths,
                    float* __restrict__ hh, unsigned int* __restrict__ flg,
                    float* __restrict__ pool)
{
    __shared__ float h_sh[2][256];
    __shared__ float zp[4][2][128];   // [ksplit][row][local gate-col]

    const int tid = threadIdx.x;
    const int wg  = blockIdx.x;
    const int bg  = wg & 15;
    const int dir = (wg >> 4) & 1;
    const int cg  = wg >> 5;          // 0..7 (teammates stride 32 -> same XCD)

    const float* P   = dir ? Pb  : Pf;
    const float* Whh = dir ? Whb : Whf;

    const int brow0 = bg * 2;
    const int len0 = lengths[brow0], len1 = lengths[brow0 + 1];
    const int tmax = max(len0, len1);

    // GEMV mapping: q = k-quarter, cl = local col in [0,128)
    const int q   = tid >> 7;
    const int cl  = tid & 127;
    const int g0  = cl >> 5;
    const int dd0 = cl & 31;
    const int gcol = g0 * 256 + cg * 32 + dd0;    // global Whh column
    const int q64 = q * 64;

    // persistent W slice: 64 floats (constant indices only!)
    float wv[64];
    {
        const float* wp = Whh + (size_t)q64 * G4_ + gcol;
#define LOADW(k) wv[k] = wp[(size_t)(k) * G4_];
        RPT64(LOADW)
#undef LOADW
    }

    // gate mapping (tid < 64): row gr, local hidden index gd
    const int gr    = tid >> 5;
    const int gd    = tid & 31;
    const int gbrow = brow0 + gr;
    const int glen  = gr ? len1 : len0;
    float cst = 0.f, hreg = 0.f, pacc = 0.f;

    // exchange bases for this (dir, bg)
    const size_t hhPar  = (size_t)2 * 16 * 512;          // floats per parity
    const size_t flPar  = (size_t)2 * 16 * 8;            // flags per parity
    float*        hhB   = hh  + ((size_t)dir * 16 + bg) * 512;
    unsigned int* flB   = flg + ((size_t)dir * 16 + bg) * 8;

    // consumer mapping: thread stages element e = tid -> (d = e>>1, row = e&1)
    // wave w covers d in [32w, 32w+32) -> producer cg' = w : ONE flag per wave
    const int wv_id = tid >> 6;                           // wave index 0..7
    const int st_d  = tid >> 1;
    const int st_r  = tid & 1;

    // producer store index (gate threads): element (cg*32+gd)*2 + gr
    const int pub_e = (cg * 32 + gd) * 2 + gr;

    for (int s = 0; s < tmax; ++s) {
        const int tt = dir ? (tmax - 1 - s) : s;
        const size_t parR = (size_t)(s & 1);

        // prefetch input projection for this step (independent of the poll)
        float pv0 = 0.f, pv1 = 0.f, pv2 = 0.f, pv3 = 0.f;
        if (tid < 64) {
            const float* pr = P + (size_t)(gbrow * T_ + tt) * G4_ + cg * 32 + gd;
            pv0 = pr[0]; pv1 = pr[256]; pv2 = pr[512]; pv3 = pr[768];
        }

        // spin on this wave's producer flag (single broadcast dword)
        {
            const unsigned int* fp = flB + parR * flPar + wv_id;
            while (__hip_atomic_load(fp, __ATOMIC_RELAXED,
                                     __HIP_MEMORY_SCOPE_AGENT) < (unsigned)s) {
            }
        }
        // fresh h element (cache-bypassing 4B atomic load), stage to LDS
        {
            const unsigned int* hp =
                (const unsigned int*)(hhB + parR * hhPar) + tid;
            const unsigned int hv = __hip_atomic_load(hp, __ATOMIC_RELAXED,
                                                      __HIP_MEMORY_SCOPE_AGENT);
            h_sh[st_r][st_d] = __uint_as_float(hv);
        }
        __syncthreads();

        // GEMV: 2 rows x 1 col over k in [64q, 64q+64)  (R4 core)
        {
            const float* hp0 = &h_sh[0][q64];
            const float* hp1 = &h_sh[1][q64];
            float a0 = 0.f, a1 = 0.f;
#define GEMV4(k4) { \
            const float4 hv0 = *(const float4*)(hp0 + 4 * (k4)); \
            const float4 hv1 = *(const float4*)(hp1 + 4 * (k4)); \
            a0 += hv0.x * wv[4*(k4)  ]; a1 += hv1.x * wv[4*(k4)  ]; \
            a0 += hv0.y * wv[4*(k4)+1]; a1 += hv1.y * wv[4*(k4)+1]; \
            a0 += hv0.z * wv[4*(k4)+2]; a1 += hv1.z * wv[4*(k4)+2]; \
            a0 += hv0.w * wv[4*(k4)+3]; a1 += hv1.w * wv[4*(k4)+3]; }
            RPT16(GEMV4, 0)
#undef GEMV4
            zp[q][0][cl] = a0;
            zp[q][1][cl] = a1;
        }
        __syncthreads();

        // gates + state + publish (wave 0 only; wave-uniform branch)
        if (tid < 64) {
            float zi = pv0 + zp[0][gr][gd]      + zp[1][gr][gd]      + zp[2][gr][gd]      + zp[3][gr][gd];
            float zf = pv1 + zp[0][gr][32 + gd] + zp[1][gr][32 + gd] + zp[2][gr][32 + gd] + zp[3][gr][32 + gd];
            float zg = pv2 + zp[0][gr][64 + gd] + zp[1][gr][64 + gd] + zp[2][gr][64 + gd] + zp[3][gr][64 + gd];
            float zo = pv3 + zp[0][gr][96 + gd] + zp[1][gr][96 + gd] + zp[2][gr][96 + gd] + zp[3][gr][96 + gd];
            const float ig = fsigm(zi);
            const float fg = fsigm(zf);
            const float gg = ftanh(zg);
            const float og = fsigm(zo);
            const float cn = fg * cst + ig * gg;
            const float hn = og * ftanh(cn);
            if (tt < glen) { cst = cn; hreg = hn; pacc += hn; }

            const size_t parW = (size_t)((s + 1) & 1);
            unsigned int* hs = (unsigned int*)(hhB + parW * hhPar) + pub_e;
            __hip_atomic_store(hs, __float_as_uint(hreg),
                               __ATOMIC_RELAXED, __HIP_MEMORY_SCOPE_AGENT);
            // order: all 64 lanes' h stores acked before the flag
            __builtin_amdgcn_fence(__ATOMIC_RELEASE, "agent");
            if (tid == 0) {
                __hip_atomic_store(flB + parW * flPar + cg, (unsigned)(s + 1),
                                   __ATOMIC_RELAXED, __HIP_MEMORY_SCOPE_AGENT);
            }
        }
        // no trailing barrier: zp of step s+1 is written only after the next
        // post-stage __syncthreads, which wave 0 reaches after this block.
    }

    if (tid < 64)
        pool[(size_t)gbrow * 512 + dir * 256 + cg * 32 + gd]
            = pacc / (float)glen;
}

// ---------------------------------------------------------------------------
// Kernel 4: fc_hidden = relu(pool @ Wfc + bfc); out = fc_hidden @ Wout + bout
// ---------------------------------------------------------------------------
__global__ __launch_bounds__(256)
void k_fc(const float* __restrict__ pool, const float* __restrict__ Wfc,
          const float* __restrict__ bfc, const float* __restrict__ Wout,
          const float* __restrict__ bout, float* __restrict__ out)
{
    __shared__ float p_sh[512];
    __shared__ float red[8];

    const int tid = threadIdx.x;
    const int b   = blockIdx.x;

    p_sh[tid]       = pool[b * 512 + tid];
    p_sh[256 + tid] = pool[b * 512 + 256 + tid];
    __syncthreads();

    float acc = bfc[tid];
#pragma unroll 8
    for (int k = 0; k < 512; ++k)
        acc += p_sh[k] * Wfc[(size_t)k * H_ + tid];
    const float fh = fmaxf(acc, 0.f);

    float p0 = fh * Wout[tid * 2 + 0];
    float p1 = fh * Wout[tid * 2 + 1];
#pragma unroll
    for (int off = 32; off > 0; off >>= 1) {
        p0 += __shfl_down(p0, off);
        p1 += __shfl_down(p1, off);
    }
    const int wave = tid >> 6;
    if ((tid & 63) == 0) { red[wave * 2] = p0; red[wave * 2 + 1] = p1; }
    __syncthreads();
    if (tid == 0) {
        out[b * 2 + 0] = red[0] + red[2] + red[4] + red[6] + bout[0];
        out[b * 2 + 1] = red[1] + red[3] + red[5] + red[7] + bout[1];
    }
}

__global__ void k_sentinel(float* out, int n)
{
    const int i = blockIdx.x * blockDim.x + threadIdx.x;
    if (i < n) out[i] = 1.0e9f;
}

extern "C" void kernel_launch(void* const* d_in, const int* in_sizes, int n_in,
                              void* d_out, int out_size, void* d_ws, size_t ws_size,
                              hipStream_t stream)
{
    const float* emb  = (const float*)d_in[0];
    const float* Win  = (const float*)d_in[1];
    const float* bin  = (const float*)d_in[2];
    const float* Wihf = (const float*)d_in[3];
    const float* Whhf = (const float*)d_in[4];
    const float* blf  = (const float*)d_in[5];
    const float* Wihb = (const float*)d_in[6];
    const float* Whhb = (const float*)d_in[7];
    const float* blb  = (const float*)d_in[8];
    const float* Wfc  = (const float*)d_in[9];
    const float* bfc  = (const float*)d_in[10];
    const float* Wout = (const float*)d_in[11];
    const float* bout = (const float*)d_in[12];
    const int*   x    = (const int*)d_in[13];
    const int*   lens = (const int*)d_in[15];
    float*       out  = (float*)d_out;

    const size_t need = ((size_t)M_ * H_ + 2 * (size_t)M_ * G4_) * sizeof(float);
    if (ws_size < need) {
        hipLaunchKernelGGL(k_sentinel, dim3(1), dim3(64), 0, stream, out, out_size);
        return;
    }

    float* z  = (float*)d_ws;                    // [16384,256] (dead after k2)
    float* Pf = z + (size_t)M_ * H_;             // [16384,1024]
    float* Pb = Pf + (size_t)M_ * G4_;           // [16384,1024]

    // overlay inside z region (init runs after k2 has consumed z)
    float*        hh   = (float*)d_ws;                   // [2][2][16][512]
    unsigned int* flgp = (unsigned int*)(hh + HHN);      // [2][2][16][8]
    float*        pool = (float*)(flgp + FLN);           // [32][512]

    hipLaunchKernelGGL(k_embed_proj, dim3(2, 128), dim3(256), 0, stream,
                       emb, Win, bin, x, z);
    hipLaunchKernelGGL(k_in_proj, dim3(8, 128, 2), dim3(256), 0, stream,
                       z, Wihf, blf, Wihb, blb, Pf, Pb);
    hipLaunchKernelGGL(k_init, dim3(128), dim3(256), 0, stream, hh, flgp);
    hipLaunchKernelGGL(k_lstm_persist, dim3(NWG), dim3(THR), 0, stream,
                       Pf, Pb, Whhf, Whhb, lens, hh, flgp, pool);
    hipLaunchKernelGGL(k_fc, dim3(32), dim3(256), 0, stream,
                       pool, Wfc, bfc, Wout, bout, out);
}